// Round 3
// baseline (106.389 us; speedup 1.0000x reference)
//
#include <hip/hip_runtime.h>
#include <cstdint>
#include <cstddef>

typedef unsigned long long u64;

// Problem constants (N,P,T,H,W) = (8,32,16,384,384)
constexpr int N_  = 8;
constexpr int P_  = 32;
constexpr int T_  = 16;
constexpr int HW  = 384 * 384;        // 147456 pixels per mask
constexpr int WORDS = HW / 64;        // 2304 u64 words per mask
constexpr int GPN = HW / 256;         // 576 256-pixel groups per image
constexpr int M_  = P_ + T_;          // 48 masks per image
constexpr int CHUNK = 6;              // pixel-groups per block
constexpr int BPN = GPN / CHUNK;      // 96 blocks per image

// ---------------------------------------------------------------------------
// Fused pack + pairwise-intersection + areas.
// One block = CHUNK pixel-groups (256 px each) of one image. Per group:
//   phase A: wave w ballots masks m = w*12..w*12+11 (float4 load -> 4 bit
//            words), stages them in LDS, accumulates per-mask area in regs,
//            and streams pred words to packed_p for the score kernel.
//   phase B: thread (p = tid>>3, tpair = tid&7) accumulates
//            popcount(pred[p] & true[t]) for t = 2*tpair, 2*tpair+1.
// Block-end: one atomicAdd per accumulator (exact ints -> deterministic).
// LDS stride 6 u64 (48 B) keeps b128 reads 16B-aligned and <=2-way banked.
// ---------------------------------------------------------------------------
__global__ __launch_bounds__(256)
void fused_pack_inter(const float* __restrict__ gp, const float* __restrict__ gt,
                      u64* __restrict__ pp, int* __restrict__ inter,
                      int* __restrict__ area) {
    __shared__ __align__(16) u64 words[M_][6];

    const int tid  = threadIdx.x;
    const int lane = tid & 63;
    const int wv   = tid >> 6;
    const int n    = blockIdx.x / BPN;
    const int g0   = (blockIdx.x - n * BPN) * CHUNK;

    const int p  = tid >> 3;          // 0..31
    const int t0 = (tid & 7) * 2;     // 0,2,..,14
    const int t1 = t0 + 1;

    int acc0 = 0, acc1 = 0;
    int areaAcc[12] = {};

    for (int c = 0; c < CHUNK; ++c) {
        const int g = g0 + c;
        #pragma unroll
        for (int k = 0; k < 12; ++k) {
            const int m = wv * 12 + k;
            const float* src = (m < P_)
                ? gp + (size_t)(n * P_ + m) * HW
                : gt + (size_t)(n * T_ + (m - P_)) * HW;
            float4 v = reinterpret_cast<const float4*>(src + (size_t)g * 256)[lane];
            u64 b0 = __ballot(v.x != 0.0f);
            u64 b1 = __ballot(v.y != 0.0f);
            u64 b2 = __ballot(v.z != 0.0f);
            u64 b3 = __ballot(v.w != 0.0f);
            areaAcc[k] += __popcll(b0) + __popcll(b1) + __popcll(b2) + __popcll(b3);
            if (lane == 0) {
                ulonglong2 w01, w23;
                w01.x = b0; w01.y = b1; w23.x = b2; w23.y = b3;
                *reinterpret_cast<ulonglong2*>(&words[m][0]) = w01;
                *reinterpret_cast<ulonglong2*>(&words[m][2]) = w23;
                if (m < P_) {
                    u64* d = pp + (size_t)(n * P_ + m) * WORDS + (size_t)g * 4;
                    *reinterpret_cast<ulonglong2*>(d)     = w01;
                    *reinterpret_cast<ulonglong2*>(d + 2) = w23;
                }
            }
        }
        __syncthreads();
        {
            ulonglong2 a01 = *reinterpret_cast<const ulonglong2*>(&words[p][0]);
            ulonglong2 a23 = *reinterpret_cast<const ulonglong2*>(&words[p][2]);
            ulonglong2 b01 = *reinterpret_cast<const ulonglong2*>(&words[P_ + t0][0]);
            ulonglong2 b23 = *reinterpret_cast<const ulonglong2*>(&words[P_ + t0][2]);
            ulonglong2 c01 = *reinterpret_cast<const ulonglong2*>(&words[P_ + t1][0]);
            ulonglong2 c23 = *reinterpret_cast<const ulonglong2*>(&words[P_ + t1][2]);
            acc0 += __popcll(a01.x & b01.x) + __popcll(a01.y & b01.y)
                  + __popcll(a23.x & b23.x) + __popcll(a23.y & b23.y);
            acc1 += __popcll(a01.x & c01.x) + __popcll(a01.y & c01.y)
                  + __popcll(a23.x & c23.x) + __popcll(a23.y & c23.y);
        }
        __syncthreads();
    }

    atomicAdd(&inter[(n * P_ + p) * T_ + t0], acc0);
    atomicAdd(&inter[(n * P_ + p) * T_ + t1], acc1);
    if (lane == 0) {
        #pragma unroll
        for (int k = 0; k < 12; ++k)
            atomicAdd(&area[n * M_ + wv * 12 + k], areaAcc[k]);
    }
}

// ---------------------------------------------------------------------------
// Per-pixel score with iou_max recomputed per block from the exact int
// tables. One block = 4 pixel-groups (1024 px) of one image; packed-pred
// words staged to LDS with coalesced loads, consumed as wave-uniform
// broadcast reads.
// ---------------------------------------------------------------------------
__global__ __launch_bounds__(256)
void score_kernel(const u64* __restrict__ pm,
                  const int* __restrict__ inter,
                  const int* __restrict__ area,
                  float* __restrict__ out) {
    __shared__ u64   wlds[P_][16];
    __shared__ float iou[P_];

    const int tid  = threadIdx.x;
    const int lane = tid & 63;
    const int wv   = tid >> 6;
    const int gblk = blockIdx.x * 4;
    const int n    = gblk / GPN;
    const int gl0  = gblk - n * GPN;

    {
        int p = tid >> 3, k = tid & 7;
        const u64* s = pm + (size_t)(n * P_ + p) * WORDS + (size_t)gl0 * 4 + 2 * k;
        *reinterpret_cast<ulonglong2*>(&wlds[p][2 * k]) =
            *reinterpret_cast<const ulonglong2*>(s);
    }

    if (tid < P_) {
        float ap = (float)area[n * M_ + tid];
        float best = 0.0f;
        #pragma unroll
        for (int t = 0; t < T_; ++t) {
            float it = (float)inter[(n * P_ + tid) * T_ + t];
            float u  = ap + (float)area[n * M_ + P_ + t] - it;
            best = fmaxf(best, (u > 0.0f) ? it / u : 0.0f);
        }
        iou[tid] = best;
    }
    __syncthreads();

    float num0 = 0.f, num1 = 0.f, num2 = 0.f, num3 = 0.f;
    int   den0 = 0, den1 = 0, den2 = 0, den3 = 0;
    #pragma unroll
    for (int p = 0; p < P_; ++p) {
        float w8 = iou[p];
        u64 w0 = wlds[p][wv * 4 + 0];   // uniform addr per wave -> broadcast
        u64 w1 = wlds[p][wv * 4 + 1];
        u64 w2 = wlds[p][wv * 4 + 2];
        u64 w3 = wlds[p][wv * 4 + 3];
        unsigned b0 = (unsigned)(w0 >> lane) & 1u;
        unsigned b1 = (unsigned)(w1 >> lane) & 1u;
        unsigned b2 = (unsigned)(w2 >> lane) & 1u;
        unsigned b3 = (unsigned)(w3 >> lane) & 1u;
        num0 += b0 ? w8 : 0.0f;  den0 += b0;
        num1 += b1 ? w8 : 0.0f;  den1 += b1;
        num2 += b2 ? w8 : 0.0f;  den2 += b2;
        num3 += b3 ? w8 : 0.0f;  den3 += b3;
    }

    float4 o;
    o.x = den0 ? num0 / (float)den0 : 0.0f;
    o.y = den1 ? num1 / (float)den1 : 0.0f;
    o.z = den2 ? num2 / (float)den2 : 0.0f;
    o.w = den3 ? num3 / (float)den3 : 0.0f;
    reinterpret_cast<float4*>(out)[(size_t)(gblk + wv) * 64 + lane] = o;
}

extern "C" void kernel_launch(void* const* d_in, const int* in_sizes, int n_in,
                              void* d_out, int out_size, void* d_ws, size_t ws_size,
                              hipStream_t stream) {
    const float* gp = (const float*)d_in[0];   // (N,P,H,W)
    const float* gt = (const float*)d_in[1];   // (N,T,H,W)
    float* out = (float*)d_out;                // (N,H,W)

    char* ws = (char*)d_ws;
    int* inter = (int*)ws;                         // 8*32*16*4 = 16384 B
    int* area  = (int*)(ws + 16384);               // 8*48*4   = 1536 B
    u64* packed_p = (u64*)(ws + 16384 + 1536);     // 17920 % 16 == 0; 4.72 MB

    // Atomic accumulators must start at zero every call (harness poisons ws
    // once and never re-poisons between graph replays).
    hipMemsetAsync(ws, 0, 16384 + 1536, stream);

    hipLaunchKernelGGL(fused_pack_inter, dim3(N_ * BPN), dim3(256), 0, stream,
                       gp, gt, packed_p, inter, area);
    hipLaunchKernelGGL(score_kernel, dim3(N_ * GPN / 4), dim3(256), 0, stream,
                       packed_p, inter, area, out);
}